// Round 16
// baseline (817.828 us; speedup 1.0000x reference)
//
#include <hip/hip_runtime.h>

#define TS 40
#define BT 64        // batch per block = 4 waves x 16
#define NT 256
#define NMT 25       // m-tiles of 16 rows ; M = 400 = 100 units x 4 gates

typedef short bf16x8 __attribute__((ext_vector_type(8)));
typedef float f32x4 __attribute__((ext_vector_type(4)));
typedef float f32x2 __attribute__((ext_vector_type(2)));

// LDS (102400 B): As[400][128] bf16, 16B-chunk XOR-swizzled by (row&7).
// Init scratch aliases it (consumed before As staged):
//   W2s@0 (40000) ; h1s@40000 (25600) ; projs@65600 (25600, ends 91200)
#define W2S_OFF  0
#define H1S_OFF  40000
#define PROJ_OFF 65600
#define SMEM_BYTES 102400

__device__ __forceinline__ unsigned short f2bf(float x) {
    unsigned u = __float_as_uint(x);
    unsigned r = u + 0x7fffu + ((u >> 16) & 1u);
    return (unsigned short)(r >> 16);
}
__device__ __forceinline__ float bf2f(unsigned short s) {
    return __uint_as_float(((unsigned)s) << 16);
}
__device__ __forceinline__ float sigf(float x) {
    return __builtin_amdgcn_rcpf(1.0f + __expf(-x));
}
__device__ __forceinline__ float tanhf_(float x) {
    return 2.0f * __builtin_amdgcn_rcpf(1.0f + __expf(-2.0f * x)) - 1.0f;
}

// Row/col permuted weight build.
// A row r (0..399): mt=r>>4, lg_r=(r>>2)&3, gate g=r&3 ; unit_row = 4*mt+lg_r ;
//   original column = g*100 + unit_row.
// K position k (0..127): kc=k>>5, lg_k=(k>>3)&3, jj=k&7.
//   jj<=6 & (mtk=4*jj+kc)<=24 : holds h-unit sigma = 4*mtk+lg_k  -> Wr (Am), Wk (Ah/Al)
//   jj==7 & (renv=4*kc+lg_k)<=8 : holds x9[renv]                 -> Wk[100+renv] (Am only)
//   else zero.
__global__ void prep_kernel(const float* __restrict__ Wr, const float* __restrict__ Wk,
                            unsigned short* __restrict__ Am, unsigned short* __restrict__ Ah,
                            unsigned short* __restrict__ Al) {
    int gid = blockIdx.x * 256 + threadIdx.x;   // 400*128 = 51200
    int r = gid >> 7, k = gid & 127;
    int mtr = r >> 4, lgr = (r >> 2) & 3, g = r & 3;
    int col = g * 100 + (4 * mtr + lgr);
    int kc = k >> 5, lgk = (k >> 3) & 3, jj = k & 7;
    float wm = 0.f, wkv = 0.f;
    if (jj <= 6) {
        int mtk = 4 * jj + kc;
        if (mtk <= 24) {
            int su = 4 * mtk + lgk;
            wm  = Wr[su * 400 + col];
            wkv = Wk[su * 400 + col];
        }
    } else {
        int renv = 4 * kc + lgk;
        if (renv <= 8) wm = Wk[(100 + renv) * 400 + col];
    }
    unsigned short hi = f2bf(wkv);
    Am[gid] = f2bf(wm);
    Ah[gid] = hi;
    Al[gid] = f2bf(wkv - bf2f(hi));
}

#define ENV_X9(c0, c1, c2, cs)                                              \
    const float f_veh_v = c0[1], m_veh_v = c0[2];                           \
    const float f_glob_x = c1[0], m_glob_x = c1[1];                         \
    const float ef_dv_t = c1[2], ef_dx_t = c1[3];                           \
    const float em_dv_t = c2[0], em_dx_t = c2[1];                           \
    const float f_ex = c2[2], m_ex = c2[3];                                 \
    const float ef_dx = (f_glob_x - ego_x) * f_ex + (1.f - f_ex) * ef_dx_t; \
    const float em_dx = (m_glob_x - ego_x) * m_ex + (1.f - m_ex) * em_dx_t; \
    const float ef_dv = (ego_v - f_veh_v) * f_ex + (1.f - f_ex) * ef_dv_t;  \
    const float em_dv = (ego_v - m_veh_v) * m_ex + (1.f - m_ex) * em_dv_t;  \
    const float x90 = cs[0], x91 = cs[1];                                   \
    const float x92 = (ego_v   - msr[0]) * isr[0];                          \
    const float x93 = (f_veh_v - msr[1]) * isr[1];                          \
    const float x94 = (m_veh_v - msr[2]) * isr[2];                          \
    const float x95 = (ef_dv   - msr[3]) * isr[3];                          \
    const float x96 = (ef_dx   - msr[4]) * isr[4];                          \
    const float x97 = (em_dv   - msr[5]) * isr[5];                          \
    const float x98 = (em_dx   - msr[6]) * isr[6];

// env slot (kc, jj=7) holds x9[4*kc + lg]
#define PACK_ENV(DH, DL)                                                    \
    {                                                                       \
        const float e0 = (lg==0)?x90:(lg==1)?x91:(lg==2)?x92:x93;           \
        const float e1 = (lg==0)?x94:(lg==1)?x95:(lg==2)?x96:x97;           \
        const float e2 = (lg==0)?x98:0.f;                                   \
        const unsigned short t0 = f2bf(e0), t1 = f2bf(e1), t2 = f2bf(e2);   \
        DH[0][7] = (short)t0; DL[0][7] = (short)f2bf(e0 - bf2f(t0));        \
        DH[1][7] = (short)t1; DL[1][7] = (short)f2bf(e1 - bf2f(t1));        \
        DH[2][7] = (short)t2; DL[2][7] = (short)f2bf(e2 - bf2f(t2));        \
        DH[3][7] = 0; DL[3][7] = 0;                                         \
    }

__global__ __launch_bounds__(NT, 1)
void fwdsim_kernel(const float* __restrict__ sampled_z,
                   const float* __restrict__ idm_s,
                   const float* __restrict__ sdv_acts,
                   const float* __restrict__ W1, const float* __restrict__ b1,
                   const float* __restrict__ W2, const float* __restrict__ b2,
                   const float* __restrict__ bl, const float* __restrict__ Wd,
                   const float* __restrict__ bd,
                   const float* __restrict__ sc_mean, const float* __restrict__ sc_var,
                   const unsigned short* __restrict__ Am,
                   const unsigned short* __restrict__ Ah,
                   const unsigned short* __restrict__ Al,
                   float* __restrict__ out) {
    __shared__ char sm[SMEM_BYTES];
    float* W2s  = (float*)(sm + W2S_OFF);
    float* h1s  = (float*)(sm + H1S_OFF);
    float* projs= (float*)(sm + PROJ_OFF);

    const int tid = threadIdx.x;
    const int w = tid >> 6, l = tid & 63, lb = l & 15, lg = l >> 4;
    const int blk = blockIdx.x;
    const int bloc = w * 16 + lb;               // 0..63 batch-in-block
    const size_t eg = (size_t)(blk * BT + bloc);

    // ---------------- init: stage W2 ; h1 = relu(z@W1+b1) ----------------
    for (int i = tid; i < 2500; i += NT) ((f32x4*)W2s)[i] = ((const f32x4*)W2)[i];
    {
        const int e = tid >> 2, q = tid & 3;    // 64 elems x 4 threads x 25 cols
        const int egi = blk * BT + e;
        float zv[6];
        #pragma unroll
        for (int r = 0; r < 6; ++r) zv[r] = sampled_z[egi * 6 + r];
        for (int m = 0; m < 25; ++m) {
            const int c = q * 25 + m;
            float a = b1[c];
            #pragma unroll
            for (int r = 0; r < 6; ++r) a += zv[r] * W1[r * 100 + c];
            h1s[e * 100 + c] = fmaxf(a, 0.f);
        }
    }
    __syncthreads();

    // ---------------- proj = relu(h1 @ W2 + b2) ----------------
    {
        const int e = tid >> 2, q = tid & 3;
        for (int m = 0; m < 25; ++m) {
            const int c = q * 25 + m;
            float a = b2[c];
            for (int k = 0; k < 100; ++k) a += h1s[e * 100 + k] * W2s[k * 100 + c];
            projs[e * 100 + c] = fmaxf(a, 0.f);
        }
    }
    __syncthreads();   // projs ready

    // ---------------- per-lane state ----------------
    float c_st[NMT], wd_reg[NMT];
    #pragma unroll
    for (int mt = 0; mt < NMT; ++mt) {
        const int u = 4 * mt + lg;              // always < 100
        wd_reg[mt] = Wd[u];
        c_st[mt]   = projs[bloc * 100 + u];
    }

    // B-frags: proj in sigma layout (h0 = proj)
    bf16x8 bh[4], bl_[4];
    #pragma unroll
    for (int kc = 0; kc < 4; ++kc) {
        bh[kc]  = (bf16x8){0,0,0,0,0,0,0,0};
        bl_[kc] = (bf16x8){0,0,0,0,0,0,0,0};
    }
    #pragma unroll
    for (int mt = 0; mt < NMT; ++mt) {
        const int kcq = mt & 3, jjq = mt >> 2;
        const float v = projs[bloc * 100 + 4 * mt + lg];
        const unsigned short hi = f2bf(v);
        bh[kcq][jjq]  = (short)hi;
        bl_[kcq][jjq] = (short)f2bf(v - bf2f(hi));
    }

    float msr[7], isr[7];
    #pragma unroll
    for (int r = 0; r < 7; ++r) { msr[r] = sc_mean[r]; isr[r] = 1.0f / sqrtf(sc_var[r]); }
    const float bd0 = bd[0];

    // ---------------- gk = bl + Wk_sigma @ proj  (A from global Ah/Al) ----------------
    f32x4 gk[NMT];
    #pragma unroll
    for (int mt = 0; mt < NMT; ++mt) {
        f32x4 ac = (f32x4){0.f, 0.f, 0.f, 0.f};
        #pragma unroll
        for (int kc = 0; kc < 4; ++kc) {
            const int row = 16 * mt + lb;
            bf16x8 ah = *(const bf16x8*)(Ah + row * 128 + kc * 32 + lg * 8);
            bf16x8 al = *(const bf16x8*)(Al + row * 128 + kc * 32 + lg * 8);
            ac = __builtin_amdgcn_mfma_f32_16x16x32_bf16(ah, bh[kc],  ac, 0, 0, 0);
            ac = __builtin_amdgcn_mfma_f32_16x16x32_bf16(ah, bl_[kc], ac, 0, 0, 0);
            ac = __builtin_amdgcn_mfma_f32_16x16x32_bf16(al, bh[kc],  ac, 0, 0, 0);
        }
        const int u = 4 * mt + lg;
        ac[0] += bl[u]; ac[1] += bl[100 + u]; ac[2] += bl[200 + u]; ac[3] += bl[300 + u];
        gk[mt] = ac;
    }
    __syncthreads();   // all projs reads done -> scratch dead

    // ---------------- stage As (swizzled) ; env t=0 in parallel ----------------
    #pragma unroll
    for (int i = 0; i < 25; ++i) {
        const int ch = tid + i * NT;            // 6400 chunks of 16B
        const int row = ch >> 4, c16 = ch & 15;
        *(bf16x8*)(sm + row * 256 + ((c16 * 16) ^ ((row & 7) << 4))) =
            *(const bf16x8*)(Am + row * 128 + c16 * 8);
    }
    float ego_v, ego_x;
    f32x4 cur0, cur1, cur2;
    f32x2 curs;
    {
        const float* ip = idm_s + (eg * TS) * 12;
        f32x4 i0 = *(const f32x4*)ip, i1 = *(const f32x4*)(ip + 4), i2 = *(const f32x4*)(ip + 8);
        f32x2 s0 = *(const f32x2*)(sdv_acts + (eg * TS) * 2);
        ego_v = i0[0]; ego_x = i0[3];
        ENV_X9(i0, i1, i2, s0)
        PACK_ENV(bh, bl_)
        const float* ip1 = idm_s + (eg * TS + 1) * 12;
        cur0 = *(const f32x4*)ip1; cur1 = *(const f32x4*)(ip1 + 4); cur2 = *(const f32x4*)(ip1 + 8);
        curs = *(const f32x2*)(sdv_acts + (eg * TS + 1) * 2);
    }
    __syncthreads();   // As ready -- LAST barrier; loop is barrier-free

    // ---------------- 40-step recurrence, fully wave-local ----------------
    const int sw = (lb & 7) << 4;
    const int k0 = (16 * lg) ^ sw;
    const int k1 = (64 + 16 * lg) ^ sw;
    const int k2 = (128 + 16 * lg) ^ sw;
    const int k3 = (192 + 16 * lg) ^ sw;
    const char* Abase = sm + lb * 256;

    for (int t = 0; t < TS; ++t) {
        bf16x8 nbh[4], nbl[4];
        float pact = 0.f;
        #pragma unroll
        for (int mt = 0; mt < NMT; ++mt) {
            const char* ap = Abase + mt * 4096;
            bf16x8 a0 = *(const bf16x8*)(ap + k0);
            f32x4 ac = __builtin_amdgcn_mfma_f32_16x16x32_bf16(a0, bh[0], gk[mt], 0, 0, 0);
            ac = __builtin_amdgcn_mfma_f32_16x16x32_bf16(a0, bl_[0], ac, 0, 0, 0);
            bf16x8 a1 = *(const bf16x8*)(ap + k1);
            ac = __builtin_amdgcn_mfma_f32_16x16x32_bf16(a1, bh[1], ac, 0, 0, 0);
            ac = __builtin_amdgcn_mfma_f32_16x16x32_bf16(a1, bl_[1], ac, 0, 0, 0);
            bf16x8 a2 = *(const bf16x8*)(ap + k2);
            ac = __builtin_amdgcn_mfma_f32_16x16x32_bf16(a2, bh[2], ac, 0, 0, 0);
            ac = __builtin_amdgcn_mfma_f32_16x16x32_bf16(a2, bl_[2], ac, 0, 0, 0);
            bf16x8 a3 = *(const bf16x8*)(ap + k3);
            ac = __builtin_amdgcn_mfma_f32_16x16x32_bf16(a3, bh[3], ac, 0, 0, 0);
            ac = __builtin_amdgcn_mfma_f32_16x16x32_bf16(a3, bl_[3], ac, 0, 0, 0);
            // gates: ac = (i,f,g,o) for unit u = 4*mt+lg of batch lb
            const float cc = sigf(ac[1]) * c_st[mt] + sigf(ac[0]) * tanhf_(ac[2]);
            const float hh = sigf(ac[3]) * tanhf_(cc);
            c_st[mt] = cc;
            pact += hh * wd_reg[mt];
            const unsigned short hhi = f2bf(hh);
            const int kcq = mt & 3, jjq = mt >> 2;
            nbh[kcq][jjq] = (short)hhi;
            nbl[kcq][jjq] = (short)f2bf(hh - bf2f(hhi));
        }
        pact += __shfl_xor(pact, 16);
        pact += __shfl_xor(pact, 32);
        const float act = pact + bd0;
        if (lg == 0) out[eg * TS + t] = act;

        if (t < TS - 1) {
            ego_v += act * 0.1f;
            ego_x += ego_v * 0.1f + 0.005f * act;
            ENV_X9(cur0, cur1, cur2, curs)
            PACK_ENV(nbh, nbl)
            // never-written slots must be zero (mtk 25..27)
            nbh[1][6] = 0; nbh[2][6] = 0; nbh[3][6] = 0;
            nbl[1][6] = 0; nbl[2][6] = 0; nbl[3][6] = 0;
            #pragma unroll
            for (int kc = 0; kc < 4; ++kc) { bh[kc] = nbh[kc]; bl_[kc] = nbl[kc]; }
            if (t < TS - 2) {
                const float* ip = idm_s + (eg * TS + t + 2) * 12;
                cur0 = *(const f32x4*)ip; cur1 = *(const f32x4*)(ip + 4); cur2 = *(const f32x4*)(ip + 8);
                curs = *(const f32x2*)(sdv_acts + (eg * TS + t + 2) * 2);
            }
        }
    }
}

extern "C" void kernel_launch(void* const* d_in, const int* in_sizes, int n_in,
                              void* d_out, int out_size, void* d_ws, size_t ws_size,
                              hipStream_t stream) {
    const float* sampled_z = (const float*)d_in[0];
    const float* idm_s     = (const float*)d_in[1];
    const float* sdv_acts  = (const float*)d_in[2];
    const float* W1        = (const float*)d_in[3];
    const float* b1        = (const float*)d_in[4];
    const float* W2        = (const float*)d_in[5];
    const float* b2        = (const float*)d_in[6];
    const float* Wk        = (const float*)d_in[7];
    const float* Wr        = (const float*)d_in[8];
    const float* bl        = (const float*)d_in[9];
    const float* Wd        = (const float*)d_in[10];
    const float* bd        = (const float*)d_in[11];
    const float* sc_mean   = (const float*)d_in[12];
    const float* sc_var    = (const float*)d_in[13];
    float* out = (float*)d_out;

    unsigned short* Am = (unsigned short*)d_ws;       // [400][128] bf16 sigma-layout
    unsigned short* Ah = Am + 400 * 128;              // Wk hi
    unsigned short* Al = Ah + 400 * 128;              // Wk lo

    hipLaunchKernelGGL(prep_kernel, dim3(200), dim3(256), 0, stream, Wr, Wk, Am, Ah, Al);
    hipLaunchKernelGGL(fwdsim_kernel, dim3(16384 / BT), dim3(NT), 0, stream,
                       sampled_z, idm_s, sdv_acts, W1, b1, W2, b2, bl, Wd, bd,
                       sc_mean, sc_var, Am, Ah, Al, out);
}

// Round 17
// 232.701 us; speedup vs baseline: 3.5145x; 3.5145x over previous
//
#include <hip/hip_runtime.h>

#define TS 40
#define BT 64        // batch per block = 4 waves x 16
#define NT 256
#define NMT 25       // m-tiles of 16 rows ; M = 400 = 100 units x 4 gates

typedef short bf16x8 __attribute__((ext_vector_type(8)));
typedef float f32x4 __attribute__((ext_vector_type(4)));
typedef float f32x2 __attribute__((ext_vector_type(2)));

// LDS (102400 B): As[400][128] bf16, 16B-chunk XOR-swizzled by (row&7).
// Init scratch aliases it (consumed before As staged):
//   W2s@0 (40000) ; h1s@40000 (25600) ; projs@65600 (25600, ends 91200)
#define W2S_OFF  0
#define H1S_OFF  40000
#define PROJ_OFF 65600
#define SMEM_BYTES 102400

__device__ __forceinline__ unsigned short f2bf(float x) {
    unsigned u = __float_as_uint(x);
    unsigned r = u + 0x7fffu + ((u >> 16) & 1u);
    return (unsigned short)(r >> 16);
}
__device__ __forceinline__ float bf2f(unsigned short s) {
    return __uint_as_float(((unsigned)s) << 16);
}
__device__ __forceinline__ float sigf(float x) {
    return __builtin_amdgcn_rcpf(1.0f + __expf(-x));
}
__device__ __forceinline__ float tanhf_(float x) {
    return 2.0f * __builtin_amdgcn_rcpf(1.0f + __expf(-2.0f * x)) - 1.0f;
}

// Row/col permuted weight build (verified R16, absmax 3.9e-3).
__global__ void prep_kernel(const float* __restrict__ Wr, const float* __restrict__ Wk,
                            unsigned short* __restrict__ Am, unsigned short* __restrict__ Ah,
                            unsigned short* __restrict__ Al) {
    int gid = blockIdx.x * 256 + threadIdx.x;   // 400*128 = 51200
    int r = gid >> 7, k = gid & 127;
    int mtr = r >> 4, lgr = (r >> 2) & 3, g = r & 3;
    int col = g * 100 + (4 * mtr + lgr);
    int kc = k >> 5, lgk = (k >> 3) & 3, jj = k & 7;
    float wm = 0.f, wkv = 0.f;
    if (jj <= 6) {
        int mtk = 4 * jj + kc;
        if (mtk <= 24) {
            int su = 4 * mtk + lgk;
            wm  = Wr[su * 400 + col];
            wkv = Wk[su * 400 + col];
        }
    } else {
        int renv = 4 * kc + lgk;
        if (renv <= 8) wm = Wk[(100 + renv) * 400 + col];
    }
    unsigned short hi = f2bf(wkv);
    Am[gid] = f2bf(wm);
    Ah[gid] = hi;
    Al[gid] = f2bf(wkv - bf2f(hi));
}

#define ENV_X9(c0, c1, c2, cs)                                              \
    const float f_veh_v = c0[1], m_veh_v = c0[2];                           \
    const float f_glob_x = c1[0], m_glob_x = c1[1];                         \
    const float ef_dv_t = c1[2], ef_dx_t = c1[3];                           \
    const float em_dv_t = c2[0], em_dx_t = c2[1];                           \
    const float f_ex = c2[2], m_ex = c2[3];                                 \
    const float ef_dx = (f_glob_x - ego_x) * f_ex + (1.f - f_ex) * ef_dx_t; \
    const float em_dx = (m_glob_x - ego_x) * m_ex + (1.f - m_ex) * em_dx_t; \
    const float ef_dv = (ego_v - f_veh_v) * f_ex + (1.f - f_ex) * ef_dv_t;  \
    const float em_dv = (ego_v - m_veh_v) * m_ex + (1.f - m_ex) * em_dv_t;  \
    const float x90 = cs[0], x91 = cs[1];                                   \
    const float x92 = (ego_v   - msr[0]) * isr[0];                          \
    const float x93 = (f_veh_v - msr[1]) * isr[1];                          \
    const float x94 = (m_veh_v - msr[2]) * isr[2];                          \
    const float x95 = (ef_dv   - msr[3]) * isr[3];                          \
    const float x96 = (ef_dx   - msr[4]) * isr[4];                          \
    const float x97 = (em_dv   - msr[5]) * isr[5];                          \
    const float x98 = (em_dx   - msr[6]) * isr[6];

// env slot (kc, jj=7) holds x9[4*kc + lg]
#define PACK_ENV(DH, DL)                                                    \
    {                                                                       \
        const float e0 = (lg==0)?x90:(lg==1)?x91:(lg==2)?x92:x93;           \
        const float e1 = (lg==0)?x94:(lg==1)?x95:(lg==2)?x96:x97;           \
        const float e2 = (lg==0)?x98:0.f;                                   \
        const unsigned short t0 = f2bf(e0), t1 = f2bf(e1), t2 = f2bf(e2);   \
        DH[0][7] = (short)t0; DL[0][7] = (short)f2bf(e0 - bf2f(t0));        \
        DH[1][7] = (short)t1; DL[1][7] = (short)f2bf(e1 - bf2f(t1));        \
        DH[2][7] = (short)t2; DL[2][7] = (short)f2bf(e2 - bf2f(t2));        \
        DH[3][7] = 0; DL[3][7] = 0;                                         \
    }

__global__ __launch_bounds__(NT, 1)
void fwdsim_kernel(const float* __restrict__ sampled_z,
                   const float* __restrict__ idm_s,
                   const float* __restrict__ sdv_acts,
                   const float* __restrict__ W1, const float* __restrict__ b1,
                   const float* __restrict__ W2, const float* __restrict__ b2,
                   const float* __restrict__ bl, const float* __restrict__ Wd,
                   const float* __restrict__ bd,
                   const float* __restrict__ sc_mean, const float* __restrict__ sc_var,
                   const unsigned short* __restrict__ Am,
                   const unsigned short* __restrict__ Ah,
                   const unsigned short* __restrict__ Al,
                   float* __restrict__ out) {
    __shared__ char sm[SMEM_BYTES];
    float* W2s  = (float*)(sm + W2S_OFF);
    float* h1s  = (float*)(sm + H1S_OFF);
    float* projs= (float*)(sm + PROJ_OFF);

    const int tid = threadIdx.x;
    const int w = tid >> 6, l = tid & 63, lb = l & 15, lg = l >> 4;
    const int blk = blockIdx.x;
    const int bloc = w * 16 + lb;               // 0..63 batch-in-block
    const size_t eg = (size_t)(blk * BT + bloc);

    // ---------------- init: stage W2 ; h1 = relu(z@W1+b1) ----------------
    for (int i = tid; i < 2500; i += NT) ((f32x4*)W2s)[i] = ((const f32x4*)W2)[i];
    {
        const int e = tid >> 2, q = tid & 3;    // 64 elems x 4 threads x 25 cols
        const int egi = blk * BT + e;
        float zv[6];
        #pragma unroll
        for (int r = 0; r < 6; ++r) zv[r] = sampled_z[egi * 6 + r];
        for (int m = 0; m < 25; ++m) {
            const int c = q * 25 + m;
            float a = b1[c];
            #pragma unroll
            for (int r = 0; r < 6; ++r) a += zv[r] * W1[r * 100 + c];
            h1s[e * 100 + c] = fmaxf(a, 0.f);
        }
    }
    __syncthreads();

    // ---------------- proj = relu(h1 @ W2 + b2) ----------------
    {
        const int e = tid >> 2, q = tid & 3;
        for (int m = 0; m < 25; ++m) {
            const int c = q * 25 + m;
            float a = b2[c];
            for (int k = 0; k < 100; ++k) a += h1s[e * 100 + k] * W2s[k * 100 + c];
            projs[e * 100 + c] = fmaxf(a, 0.f);
        }
    }
    __syncthreads();   // projs ready

    // ---------------- per-lane state ----------------
    float c_st[NMT], wd_reg[NMT];
    #pragma unroll
    for (int mt = 0; mt < NMT; ++mt) {
        const int u = 4 * mt + lg;              // always < 100
        wd_reg[mt] = Wd[u];
        c_st[mt]   = projs[bloc * 100 + u];
    }

    // B-frags: proj in sigma layout (h0 = proj)
    bf16x8 bh[4], bl_[4];
    #pragma unroll
    for (int kc = 0; kc < 4; ++kc) {
        bh[kc]  = (bf16x8){0,0,0,0,0,0,0,0};
        bl_[kc] = (bf16x8){0,0,0,0,0,0,0,0};
    }
    #pragma unroll
    for (int mt = 0; mt < NMT; ++mt) {
        const int kcq = mt & 3, jjq = mt >> 2;
        const float v = projs[bloc * 100 + 4 * mt + lg];
        const unsigned short hi = f2bf(v);
        bh[kcq][jjq]  = (short)hi;
        bl_[kcq][jjq] = (short)f2bf(v - bf2f(hi));
    }

    float msr[7], isr[7];
    #pragma unroll
    for (int r = 0; r < 7; ++r) { msr[r] = sc_mean[r]; isr[r] = 1.0f / sqrtf(sc_var[r]); }
    const float bd0 = bd[0];

    // ---------------- gk = bl + Wk_sigma @ proj -> AGPRs ----------------
    // 100 floats/lane stashed in the accumulator half of the unified RF so the
    // arch-VGPR side stays under 256 (R16 spilled gk to scratch: 917 MB FETCH).
    float gka[NMT * 4];
    #pragma unroll
    for (int mt = 0; mt < NMT; ++mt) {
        f32x4 ac = (f32x4){0.f, 0.f, 0.f, 0.f};
        #pragma unroll
        for (int kc = 0; kc < 4; ++kc) {
            const int row = 16 * mt + lb;
            bf16x8 ah = *(const bf16x8*)(Ah + row * 128 + kc * 32 + lg * 8);
            bf16x8 al = *(const bf16x8*)(Al + row * 128 + kc * 32 + lg * 8);
            ac = __builtin_amdgcn_mfma_f32_16x16x32_bf16(ah, bh[kc],  ac, 0, 0, 0);
            ac = __builtin_amdgcn_mfma_f32_16x16x32_bf16(ah, bl_[kc], ac, 0, 0, 0);
            ac = __builtin_amdgcn_mfma_f32_16x16x32_bf16(al, bh[kc],  ac, 0, 0, 0);
        }
        const int u = 4 * mt + lg;
        const float g0 = ac[0] + bl[u];
        const float g1 = ac[1] + bl[100 + u];
        const float g2 = ac[2] + bl[200 + u];
        const float g3 = ac[3] + bl[300 + u];
        asm volatile("v_accvgpr_write_b32 %0, %1" : "=a"(gka[4 * mt + 0]) : "v"(g0));
        asm volatile("v_accvgpr_write_b32 %0, %1" : "=a"(gka[4 * mt + 1]) : "v"(g1));
        asm volatile("v_accvgpr_write_b32 %0, %1" : "=a"(gka[4 * mt + 2]) : "v"(g2));
        asm volatile("v_accvgpr_write_b32 %0, %1" : "=a"(gka[4 * mt + 3]) : "v"(g3));
    }
    __syncthreads();   // all projs reads done -> scratch dead

    // ---------------- stage As (swizzled) ; env t=0 in parallel ----------------
    #pragma unroll
    for (int i = 0; i < 25; ++i) {
        const int ch = tid + i * NT;            // 6400 chunks of 16B
        const int row = ch >> 4, c16 = ch & 15;
        *(bf16x8*)(sm + row * 256 + ((c16 * 16) ^ ((row & 7) << 4))) =
            *(const bf16x8*)(Am + row * 128 + c16 * 8);
    }
    float ego_v, ego_x;
    f32x4 cur0, cur1, cur2;
    f32x2 curs;
    {
        const float* ip = idm_s + (eg * TS) * 12;
        f32x4 i0 = *(const f32x4*)ip, i1 = *(const f32x4*)(ip + 4), i2 = *(const f32x4*)(ip + 8);
        f32x2 s0 = *(const f32x2*)(sdv_acts + (eg * TS) * 2);
        ego_v = i0[0]; ego_x = i0[3];
        ENV_X9(i0, i1, i2, s0)
        PACK_ENV(bh, bl_)
        const float* ip1 = idm_s + (eg * TS + 1) * 12;
        cur0 = *(const f32x4*)ip1; cur1 = *(const f32x4*)(ip1 + 4); cur2 = *(const f32x4*)(ip1 + 8);
        curs = *(const f32x2*)(sdv_acts + (eg * TS + 1) * 2);
    }
    __syncthreads();   // As ready -- LAST barrier; loop is barrier-free

    // ---------------- 40-step recurrence, fully wave-local ----------------
    const int sw = (lb & 7) << 4;
    const int k0 = (16 * lg) ^ sw;
    const int k1 = (64 + 16 * lg) ^ sw;
    const int k2 = (128 + 16 * lg) ^ sw;
    const int k3 = (192 + 16 * lg) ^ sw;
    const char* Abase = sm + lb * 256;

    for (int t = 0; t < TS; ++t) {
        bf16x8 nbh[4], nbl[4];
        float pact = 0.f;
        #pragma unroll
        for (int mt = 0; mt < NMT; ++mt) {
            const char* ap = Abase + mt * 4096;
            float g0, g1, g2, g3;
            asm("v_accvgpr_read_b32 %0, %1" : "=v"(g0) : "a"(gka[4 * mt + 0]));
            asm("v_accvgpr_read_b32 %0, %1" : "=v"(g1) : "a"(gka[4 * mt + 1]));
            asm("v_accvgpr_read_b32 %0, %1" : "=v"(g2) : "a"(gka[4 * mt + 2]));
            asm("v_accvgpr_read_b32 %0, %1" : "=v"(g3) : "a"(gka[4 * mt + 3]));
            f32x4 ac = (f32x4){g0, g1, g2, g3};
            bf16x8 a0 = *(const bf16x8*)(ap + k0);
            ac = __builtin_amdgcn_mfma_f32_16x16x32_bf16(a0, bh[0],  ac, 0, 0, 0);
            ac = __builtin_amdgcn_mfma_f32_16x16x32_bf16(a0, bl_[0], ac, 0, 0, 0);
            bf16x8 a1 = *(const bf16x8*)(ap + k1);
            ac = __builtin_amdgcn_mfma_f32_16x16x32_bf16(a1, bh[1],  ac, 0, 0, 0);
            ac = __builtin_amdgcn_mfma_f32_16x16x32_bf16(a1, bl_[1], ac, 0, 0, 0);
            bf16x8 a2 = *(const bf16x8*)(ap + k2);
            ac = __builtin_amdgcn_mfma_f32_16x16x32_bf16(a2, bh[2],  ac, 0, 0, 0);
            ac = __builtin_amdgcn_mfma_f32_16x16x32_bf16(a2, bl_[2], ac, 0, 0, 0);
            bf16x8 a3 = *(const bf16x8*)(ap + k3);
            ac = __builtin_amdgcn_mfma_f32_16x16x32_bf16(a3, bh[3],  ac, 0, 0, 0);
            ac = __builtin_amdgcn_mfma_f32_16x16x32_bf16(a3, bl_[3], ac, 0, 0, 0);
            // gates: ac = (i,f,g,o) for unit u = 4*mt+lg of batch lb
            const float cc = sigf(ac[1]) * c_st[mt] + sigf(ac[0]) * tanhf_(ac[2]);
            const float hh = sigf(ac[3]) * tanhf_(cc);
            c_st[mt] = cc;
            pact += hh * wd_reg[mt];
            const unsigned short hhi = f2bf(hh);
            const int kcq = mt & 3, jjq = mt >> 2;
            nbh[kcq][jjq] = (short)hhi;
            nbl[kcq][jjq] = (short)f2bf(hh - bf2f(hhi));
        }
        pact += __shfl_xor(pact, 16);
        pact += __shfl_xor(pact, 32);
        const float act = pact + bd0;
        if (lg == 0) out[eg * TS + t] = act;

        if (t < TS - 1) {
            ego_v += act * 0.1f;
            ego_x += ego_v * 0.1f + 0.005f * act;
            ENV_X9(cur0, cur1, cur2, curs)
            PACK_ENV(nbh, nbl)
            // never-written slots must be zero (mtk 25..27)
            nbh[1][6] = 0; nbh[2][6] = 0; nbh[3][6] = 0;
            nbl[1][6] = 0; nbl[2][6] = 0; nbl[3][6] = 0;
            #pragma unroll
            for (int kc = 0; kc < 4; ++kc) { bh[kc] = nbh[kc]; bl_[kc] = nbl[kc]; }
            if (t < TS - 2) {
                const float* ip = idm_s + (eg * TS + t + 2) * 12;
                cur0 = *(const f32x4*)ip; cur1 = *(const f32x4*)(ip + 4); cur2 = *(const f32x4*)(ip + 8);
                curs = *(const f32x2*)(sdv_acts + (eg * TS + t + 2) * 2);
            }
        }
    }
}

extern "C" void kernel_launch(void* const* d_in, const int* in_sizes, int n_in,
                              void* d_out, int out_size, void* d_ws, size_t ws_size,
                              hipStream_t stream) {
    const float* sampled_z = (const float*)d_in[0];
    const float* idm_s     = (const float*)d_in[1];
    const float* sdv_acts  = (const float*)d_in[2];
    const float* W1        = (const float*)d_in[3];
    const float* b1        = (const float*)d_in[4];
    const float* W2        = (const float*)d_in[5];
    const float* b2        = (const float*)d_in[6];
    const float* Wk        = (const float*)d_in[7];
    const float* Wr        = (const float*)d_in[8];
    const float* bl        = (const float*)d_in[9];
    const float* Wd        = (const float*)d_in[10];
    const float* bd        = (const float*)d_in[11];
    const float* sc_mean   = (const float*)d_in[12];
    const float* sc_var    = (const float*)d_in[13];
    float* out = (float*)d_out;

    unsigned short* Am = (unsigned short*)d_ws;       // [400][128] bf16 sigma-layout
    unsigned short* Ah = Am + 400 * 128;              // Wk hi
    unsigned short* Al = Ah + 400 * 128;              // Wk lo

    hipLaunchKernelGGL(prep_kernel, dim3(200), dim3(256), 0, stream, Wr, Wk, Am, Ah, Al);
    hipLaunchKernelGGL(fwdsim_kernel, dim3(16384 / BT), dim3(NT), 0, stream,
                       sampled_z, idm_s, sdv_acts, W1, b1, W2, b2, bl, Wd, bd,
                       sc_mean, sc_var, Am, Ah, Al, out);
}

// Round 23
// 209.466 us; speedup vs baseline: 3.9043x; 1.1109x over previous
//
#include <hip/hip_runtime.h>

#define TS 40
#define BT 64        // batch per block = 4 waves x 16
#define NT 256
#define NMT 25       // m-tiles of 16 rows ; M = 400 = 100 units x 4 gates

typedef short bf16x8 __attribute__((ext_vector_type(8)));
typedef float f32x4 __attribute__((ext_vector_type(4)));
typedef float f32x2 __attribute__((ext_vector_type(2)));

// LDS (102400 B): As[400][128] bf16, 16B-chunk XOR-swizzled by (row&7).
// Init scratch aliases it: W2s@0 (40000) ; h1s@40000 (25600) ; projs@65600 (25600)
#define W2S_OFF  0
#define H1S_OFF  40000
#define PROJ_OFF 65600
#define SMEM_BYTES 102400

__device__ __forceinline__ unsigned short f2bf(float x) {
    unsigned u = __float_as_uint(x);
    unsigned r = u + 0x7fffu + ((u >> 16) & 1u);
    return (unsigned short)(r >> 16);
}
__device__ __forceinline__ float bf2f(unsigned short s) {
    return __uint_as_float(((unsigned)s) << 16);
}
__device__ __forceinline__ float sigf(float x) {
    return __builtin_amdgcn_rcpf(1.0f + __expf(-x));
}
__device__ __forceinline__ float tanhf_(float x) {
    return 2.0f * __builtin_amdgcn_rcpf(1.0f + __expf(-2.0f * x)) - 1.0f;
}

// Row/col permuted weight build (verified R16/R17, absmax 3.9e-3).
__global__ void prep_kernel(const float* __restrict__ Wr, const float* __restrict__ Wk,
                            unsigned short* __restrict__ Am, unsigned short* __restrict__ Ah,
                            unsigned short* __restrict__ Al) {
    int gid = blockIdx.x * 256 + threadIdx.x;   // 400*128 = 51200
    int r = gid >> 7, k = gid & 127;
    int mtr = r >> 4, lgr = (r >> 2) & 3, g = r & 3;
    int col = g * 100 + (4 * mtr + lgr);
    int kc = k >> 5, lgk = (k >> 3) & 3, jj = k & 7;
    float wm = 0.f, wkv = 0.f;
    if (jj <= 6) {
        int mtk = 4 * jj + kc;
        if (mtk <= 24) {
            int su = 4 * mtk + lgk;
            wm  = Wr[su * 400 + col];
            wkv = Wk[su * 400 + col];
        }
    } else {
        int renv = 4 * kc + lgk;
        if (renv <= 8) wm = Wk[(100 + renv) * 400 + col];
    }
    unsigned short hi = f2bf(wkv);
    Am[gid] = f2bf(wm);
    Ah[gid] = hi;
    Al[gid] = f2bf(wkv - bf2f(hi));
}

#define ENV_X9(c0, c1, c2, cs)                                              \
    const float f_veh_v = c0[1], m_veh_v = c0[2];                           \
    const float f_glob_x = c1[0], m_glob_x = c1[1];                         \
    const float ef_dv_t = c1[2], ef_dx_t = c1[3];                           \
    const float em_dv_t = c2[0], em_dx_t = c2[1];                           \
    const float f_ex = c2[2], m_ex = c2[3];                                 \
    const float ef_dx = (f_glob_x - ego_x) * f_ex + (1.f - f_ex) * ef_dx_t; \
    const float em_dx = (m_glob_x - ego_x) * m_ex + (1.f - m_ex) * em_dx_t; \
    const float ef_dv = (ego_v - f_veh_v) * f_ex + (1.f - f_ex) * ef_dv_t;  \
    const float em_dv = (ego_v - m_veh_v) * m_ex + (1.f - m_ex) * em_dv_t;  \
    const float x90 = cs[0], x91 = cs[1];                                   \
    const float x92 = (ego_v   - msr[0]) * isr[0];                          \
    const float x93 = (f_veh_v - msr[1]) * isr[1];                          \
    const float x94 = (m_veh_v - msr[2]) * isr[2];                          \
    const float x95 = (ef_dv   - msr[3]) * isr[3];                          \
    const float x96 = (ef_dx   - msr[4]) * isr[4];                          \
    const float x97 = (em_dv   - msr[5]) * isr[5];                          \
    const float x98 = (em_dx   - msr[6]) * isr[6];

// env slot (kc, jj=7) holds x9[4*kc + lg] -- hi only (loop runs single-stream)
#define PACK_ENV_HI(DH)                                                     \
    {                                                                       \
        const float e0 = (lg==0)?x90:(lg==1)?x91:(lg==2)?x92:x93;           \
        const float e1 = (lg==0)?x94:(lg==1)?x95:(lg==2)?x96:x97;           \
        const float e2 = (lg==0)?x98:0.f;                                   \
        DH[0][7] = (short)f2bf(e0);                                         \
        DH[1][7] = (short)f2bf(e1);                                         \
        DH[2][7] = (short)f2bf(e2);                                         \
        DH[3][7] = 0;                                                       \
    }

__global__ __launch_bounds__(NT, 1)
void fwdsim_kernel(const float* __restrict__ sampled_z,
                   const float* __restrict__ idm_s,
                   const float* __restrict__ sdv_acts,
                   const float* __restrict__ W1, const float* __restrict__ b1,
                   const float* __restrict__ W2, const float* __restrict__ b2,
                   const float* __restrict__ bl, const float* __restrict__ Wd,
                   const float* __restrict__ bd,
                   const float* __restrict__ sc_mean, const float* __restrict__ sc_var,
                   const unsigned short* __restrict__ Am,
                   const unsigned short* __restrict__ Ah,
                   const unsigned short* __restrict__ Al,
                   float* __restrict__ out) {
    __shared__ char sm[SMEM_BYTES];
    float* W2s  = (float*)(sm + W2S_OFF);
    float* h1s  = (float*)(sm + H1S_OFF);
    float* projs= (float*)(sm + PROJ_OFF);

    const int tid = threadIdx.x;
    const int w = tid >> 6, l = tid & 63, lb = l & 15, lg = l >> 4;
    const int blk = blockIdx.x;
    const int bloc = w * 16 + lb;               // 0..63 batch-in-block
    const size_t eg = (size_t)(blk * BT + bloc);

    // ---------------- init: stage W2 ; h1 = relu(z@W1+b1) ----------------
    for (int i = tid; i < 2500; i += NT) ((f32x4*)W2s)[i] = ((const f32x4*)W2)[i];
    {
        const int e = tid >> 2, q = tid & 3;    // 64 elems x 4 threads x 25 cols
        const int egi = blk * BT + e;
        float zv[6];
        #pragma unroll
        for (int r = 0; r < 6; ++r) zv[r] = sampled_z[egi * 6 + r];
        for (int m = 0; m < 25; ++m) {
            const int c = q * 25 + m;
            float a = b1[c];
            #pragma unroll
            for (int r = 0; r < 6; ++r) a += zv[r] * W1[r * 100 + c];
            h1s[e * 100 + c] = fmaxf(a, 0.f);
        }
    }
    __syncthreads();

    // ---------------- proj = relu(h1 @ W2 + b2) ----------------
    {
        const int e = tid >> 2, q = tid & 3;
        for (int m = 0; m < 25; ++m) {
            const int c = q * 25 + m;
            float a = b2[c];
            for (int k = 0; k < 100; ++k) a += h1s[e * 100 + k] * W2s[k * 100 + c];
            projs[e * 100 + c] = fmaxf(a, 0.f);
        }
    }
    __syncthreads();   // projs ready

    // ---------------- per-lane state ----------------
    float c_st[NMT], wd_reg[NMT];
    #pragma unroll
    for (int mt = 0; mt < NMT; ++mt) {
        const int u = 4 * mt + lg;              // always < 100
        wd_reg[mt] = Wd[u];
        c_st[mt]   = projs[bloc * 100 + u];
    }

    // B-frags: proj in sigma layout (h0 = proj); bl_ used only for gk init
    bf16x8 bh[4], bl_[4];
    #pragma unroll
    for (int kc = 0; kc < 4; ++kc) {
        bh[kc]  = (bf16x8){0,0,0,0,0,0,0,0};
        bl_[kc] = (bf16x8){0,0,0,0,0,0,0,0};
    }
    #pragma unroll
    for (int mt = 0; mt < NMT; ++mt) {
        const int kcq = mt & 3, jjq = mt >> 2;
        const float v = projs[bloc * 100 + 4 * mt + lg];
        const unsigned short hi = f2bf(v);
        bh[kcq][jjq]  = (short)hi;
        bl_[kcq][jjq] = (short)f2bf(v - bf2f(hi));
    }

    float msr[7], isr[7];
    #pragma unroll
    for (int r = 0; r < 7; ++r) { msr[r] = sc_mean[r]; isr[r] = 1.0f / sqrtf(sc_var[r]); }
    const float bd0 = bd[0];

    // ---------------- gk = bl + Wk_sigma @ proj -> AGPRs (full hi/lo precision) ----------------
    float gka[NMT * 4];
    #pragma unroll
    for (int mt = 0; mt < NMT; ++mt) {
        f32x4 ac = (f32x4){0.f, 0.f, 0.f, 0.f};
        #pragma unroll
        for (int kc = 0; kc < 4; ++kc) {
            const int row = 16 * mt + lb;
            bf16x8 ah = *(const bf16x8*)(Ah + row * 128 + kc * 32 + lg * 8);
            bf16x8 al = *(const bf16x8*)(Al + row * 128 + kc * 32 + lg * 8);
            ac = __builtin_amdgcn_mfma_f32_16x16x32_bf16(ah, bh[kc],  ac, 0, 0, 0);
            ac = __builtin_amdgcn_mfma_f32_16x16x32_bf16(ah, bl_[kc], ac, 0, 0, 0);
            ac = __builtin_amdgcn_mfma_f32_16x16x32_bf16(al, bh[kc],  ac, 0, 0, 0);
        }
        const int u = 4 * mt + lg;
        const float g0 = ac[0] + bl[u];
        const float g1 = ac[1] + bl[100 + u];
        const float g2 = ac[2] + bl[200 + u];
        const float g3 = ac[3] + bl[300 + u];
        asm volatile("v_accvgpr_write_b32 %0, %1" : "=a"(gka[4 * mt + 0]) : "v"(g0));
        asm volatile("v_accvgpr_write_b32 %0, %1" : "=a"(gka[4 * mt + 1]) : "v"(g1));
        asm volatile("v_accvgpr_write_b32 %0, %1" : "=a"(gka[4 * mt + 2]) : "v"(g2));
        asm volatile("v_accvgpr_write_b32 %0, %1" : "=a"(gka[4 * mt + 3]) : "v"(g3));
    }
    __syncthreads();   // all projs reads done -> scratch dead

    // ---------------- stage As (swizzled) ; env t=0 in parallel ----------------
    #pragma unroll
    for (int i = 0; i < 25; ++i) {
        const int ch = tid + i * NT;            // 6400 chunks of 16B
        const int row = ch >> 4, c16 = ch & 15;
        *(bf16x8*)(sm + row * 256 + ((c16 * 16) ^ ((row & 7) << 4))) =
            *(const bf16x8*)(Am + row * 128 + c16 * 8);
    }
    float ego_v, ego_x;
    f32x4 cur0, cur1, cur2;
    f32x2 curs;
    {
        const float* ip = idm_s + (eg * TS) * 12;
        f32x4 i0 = *(const f32x4*)ip, i1 = *(const f32x4*)(ip + 4), i2 = *(const f32x4*)(ip + 8);
        f32x2 s0 = *(const f32x2*)(sdv_acts + (eg * TS) * 2);
        ego_v = i0[0]; ego_x = i0[3];
        ENV_X9(i0, i1, i2, s0)
        PACK_ENV_HI(bh)
        const float* ip1 = idm_s + (eg * TS + 1) * 12;
        cur0 = *(const f32x4*)ip1; cur1 = *(const f32x4*)(ip1 + 4); cur2 = *(const f32x4*)(ip1 + 8);
        curs = *(const f32x2*)(sdv_acts + (eg * TS + 1) * 2);
    }
    __syncthreads();   // As ready -- LAST barrier; loop is barrier-free

    // ---------------- 40-step recurrence, wave-local, single bf16 stream ----------------
    const int sw = (lb & 7) << 4;
    const int k0 = (16 * lg) ^ sw;
    const int k1 = (64 + 16 * lg) ^ sw;
    const int k2 = (128 + 16 * lg) ^ sw;
    const int k3 = (192 + 16 * lg) ^ sw;
    const char* Abase = sm + lb * 256;

    for (int t = 0; t < TS; ++t) {
        bf16x8 nbh[4];
        float pact = 0.f;
        #pragma unroll
        for (int mt = 0; mt < NMT; ++mt) {
            float g0, g1, g2, g3;
            asm("v_accvgpr_read_b32 %0, %1" : "=v"(g0) : "a"(gka[4 * mt + 0]));
            asm("v_accvgpr_read_b32 %0, %1" : "=v"(g1) : "a"(gka[4 * mt + 1]));
            asm("v_accvgpr_read_b32 %0, %1" : "=v"(g2) : "a"(gka[4 * mt + 2]));
            asm("v_accvgpr_read_b32 %0, %1" : "=v"(g3) : "a"(gka[4 * mt + 3]));
            f32x4 ac = (f32x4){g0, g1, g2, g3};
            const char* ap = Abase + mt * 4096;
            bf16x8 a0 = *(const bf16x8*)(ap + k0);
            ac = __builtin_amdgcn_mfma_f32_16x16x32_bf16(a0, bh[0], ac, 0, 0, 0);
            bf16x8 a1 = *(const bf16x8*)(ap + k1);
            ac = __builtin_amdgcn_mfma_f32_16x16x32_bf16(a1, bh[1], ac, 0, 0, 0);
            bf16x8 a2 = *(const bf16x8*)(ap + k2);
            ac = __builtin_amdgcn_mfma_f32_16x16x32_bf16(a2, bh[2], ac, 0, 0, 0);
            bf16x8 a3 = *(const bf16x8*)(ap + k3);
            ac = __builtin_amdgcn_mfma_f32_16x16x32_bf16(a3, bh[3], ac, 0, 0, 0);
            // gates: ac = (i,f,g,o) for unit u = 4*mt+lg of batch lb
            const float cc = sigf(ac[1]) * c_st[mt] + sigf(ac[0]) * tanhf_(ac[2]);
            const float hh = sigf(ac[3]) * tanhf_(cc);
            c_st[mt] = cc;
            pact += hh * wd_reg[mt];
            const int kcq = mt & 3, jjq = mt >> 2;
            nbh[kcq][jjq] = (short)f2bf(hh);
        }
        pact += __shfl_xor(pact, 16);
        pact += __shfl_xor(pact, 32);
        const float act = pact + bd0;
        if (lg == 0) out[eg * TS + t] = act;

        if (t < TS - 1) {
            ego_v += act * 0.1f;
            ego_x += ego_v * 0.1f + 0.005f * act;
            ENV_X9(cur0, cur1, cur2, curs)
            PACK_ENV_HI(nbh)
            // never-written slots must be zero (mtk 25..27)
            nbh[1][6] = 0; nbh[2][6] = 0; nbh[3][6] = 0;
            #pragma unroll
            for (int kc = 0; kc < 4; ++kc) bh[kc] = nbh[kc];
            if (t < TS - 2) {
                const float* ip = idm_s + (eg * TS + t + 2) * 12;
                cur0 = *(const f32x4*)ip; cur1 = *(const f32x4*)(ip + 4); cur2 = *(const f32x4*)(ip + 8);
                curs = *(const f32x2*)(sdv_acts + (eg * TS + t + 2) * 2);
            }
        }
    }
}

extern "C" void kernel_launch(void* const* d_in, const int* in_sizes, int n_in,
                              void* d_out, int out_size, void* d_ws, size_t ws_size,
                              hipStream_t stream) {
    const float* sampled_z = (const float*)d_in[0];
    const float* idm_s     = (const float*)d_in[1];
    const float* sdv_acts  = (const float*)d_in[2];
    const float* W1        = (const float*)d_in[3];
    const float* b1        = (const float*)d_in[4];
    const float* W2        = (const float*)d_in[5];
    const float* b2        = (const float*)d_in[6];
    const float* Wk        = (const float*)d_in[7];
    const float* Wr        = (const float*)d_in[8];
    const float* bl        = (const float*)d_in[9];
    const float* Wd        = (const float*)d_in[10];
    const float* bd        = (const float*)d_in[11];
    const float* sc_mean   = (const float*)d_in[12];
    const float* sc_var    = (const float*)d_in[13];
    float* out = (float*)d_out;

    unsigned short* Am = (unsigned short*)d_ws;       // [400][128] bf16 sigma-layout
    unsigned short* Ah = Am + 400 * 128;              // Wk hi
    unsigned short* Al = Ah + 400 * 128;              // Wk lo

    hipLaunchKernelGGL(prep_kernel, dim3(200), dim3(256), 0, stream, Wr, Wk, Am, Ah, Al);
    hipLaunchKernelGGL(fwdsim_kernel, dim3(16384 / BT), dim3(NT), 0, stream,
                       sampled_z, idm_s, sdv_acts, W1, b1, W2, b2, bl, Wd, bd,
                       sc_mean, sc_var, Am, Ah, Al, out);
}